// Round 2
// baseline (235.830 us; speedup 1.0000x reference)
//
#include <hip/hip_runtime.h>
#include <math.h>

#define NUM_AGENTS 256
#define HIDDEN 1024
#define RANK 32
#define NTOK 8192
#define SPLITS 8
#define RANGE (NTOK / SPLITS)   // 1024 tokens per range-split
#define TBATCH 4
#define ALPHA_MAX 5.0f
#define LN_EPS 1e-5f

// plain-vector alias: __builtin_nontemporal_* rejects HIP_vector_type
typedef float f32x4 __attribute__((ext_vector_type(4)));

// Grid: 256 agents x 8 token-range splits = 2048 blocks, 256 threads.
// Each block: scan its 1024-token id range, collect tokens of its agent,
// process them in groups of 4 with register-batched matvecs:
//   inter[m] = h[m] . U[a];  pert[m] = inter[m] . V[a];
//   out[m] = LayerNorm(h[m] + alpha*pert[m]) * gamma + beta
//
// v2 changes vs previous session:
//  - NO runtime-indexed register arrays (previous version spilled dmv/s/q to
//    scratch every group: the 45 MB WRITE_SIZE excess). All loops over m are
//    compile-time unrolled with a uniform `if (m < nm)` guard.
//  - __launch_bounds__(256, 5): ~100 VGPR budget so unroll-8 load batches
//    stay in registers (previous 64-VGPR box).
//  - LDS squeezed to exactly 20480 B (ushort toklist; inter/wred/tokcount
//    aliased into red[] with barrier-separated lifetimes).
//  - Non-temporal h loads (read-once, keep L2 for U/V) and out stores (no RFO).
//  - One int4 scan load per thread; one fewer barrier per group (stats
//    computed redundantly per-thread); conditional end-of-loop barrier.
__global__ __launch_bounds__(256, 5) void div_inject_kernel(
    const float* __restrict__ hglob,
    const float* __restrict__ log_alpha,
    const float* __restrict__ gamma,
    const float* __restrict__ beta,
    const float* __restrict__ U,
    const float* __restrict__ V,
    const int* __restrict__ ids,
    float* __restrict__ out)
{
    __shared__ __align__(16) float Hs[TBATCH][HIDDEN];     // 16384 B
    __shared__ __align__(16) float red[4][TBATCH][RANK];   //  2048 B (aliased below)
    __shared__ unsigned short toklist[RANGE];              //  2048 B
    // red[] lifetime plan (all transitions barrier-separated):
    //   scan:    red[3][0][0] = tokcount (read into reg before any red write)
    //   phase2:  red[w][m][r] = per-wave partial inter
    //   merge:   red[0][m][r] = inter (summed)        <- read through phase 3
    //   LN:      red[1][0][0..31] = wred[w][s][m]     <- disjoint from red[0]
    int* tokcount = (int*)&red[3][0][0];
    float* inter = &red[0][0][0];                                  // [TBATCH][RANK]
    float (*wred)[2][TBATCH] = reinterpret_cast<float (*)[2][TBATCH]>(&red[1][0][0]);

    const int t = threadIdx.x;
    const int agent = blockIdx.x & (NUM_AGENTS - 1);
    const int base = (blockIdx.x >> 8) * RANGE;

    if (t == 0) *tokcount = 0;
    __syncthreads();

    // ---- collect this agent's tokens: one int4 per thread covers RANGE ----
    {
        int4 iv = ((const int4*)(ids + base))[t];
        if ((iv.x & (NUM_AGENTS - 1)) == agent) toklist[atomicAdd(tokcount, 1)] = (unsigned short)(4 * t + 0);
        if ((iv.y & (NUM_AGENTS - 1)) == agent) toklist[atomicAdd(tokcount, 1)] = (unsigned short)(4 * t + 1);
        if ((iv.z & (NUM_AGENTS - 1)) == agent) toklist[atomicAdd(tokcount, 1)] = (unsigned short)(4 * t + 2);
        if ((iv.w & (NUM_AGENTS - 1)) == agent) toklist[atomicAdd(tokcount, 1)] = (unsigned short)(4 * t + 3);
    }
    __syncthreads();
    const int cnt = *tokcount;        // into a register before red[] is reused
    if (cnt == 0) return;

    const float alpha = fminf(__expf(log_alpha[0]), ALPHA_MAX);

    const float* Ua = U + (size_t)agent * (HIDDEN * RANK);
    const float* Va = V + (size_t)agent * (RANK * HIDDEN);

    const int r4 = (t & 7) * 4;   // rank quad: 0,4,...,28
    const int ks = t >> 3;        // k-slice 0..31
    const int c  = t * 4;         // this thread's 4 output columns
    const int wave = t >> 6, lane = t & 63;

    const float4 gv = *(const float4*)(gamma + c);
    const float4 bv = *(const float4*)(beta + c);

    for (int g = 0; g < cnt; g += TBATCH) {
        const int nm = min(TBATCH, cnt - g);
        int tk[TBATCH];
        #pragma unroll
        for (int m = 0; m < TBATCH; ++m)
            tk[m] = base + (int)toklist[g + min(m, nm - 1)];   // pad by replication

        // ---- stage TBATCH h rows into LDS (h is read-once: non-temporal) ----
        #pragma unroll
        for (int m = 0; m < TBATCH; ++m) {
            f32x4 hv = __builtin_nontemporal_load((const f32x4*)(hglob + (size_t)tk[m] * HIDDEN + c));
            *(f32x4*)(&Hs[m][c]) = hv;
        }
        __syncthreads();

        // ---- phase 2: inter[m][r] = sum_hh Hs[m][hh] * U[hh][r] ----
        float4 acc[TBATCH];
        #pragma unroll
        for (int m = 0; m < TBATCH; ++m) acc[m] = make_float4(0.f, 0.f, 0.f, 0.f);
        #pragma unroll 8
        for (int hh = ks; hh < HIDDEN; hh += 32) {
            float4 u = *(const float4*)(Ua + hh * RANK + r4);
            #pragma unroll
            for (int m = 0; m < TBATCH; ++m) {
                float hv = Hs[m][hh];
                acc[m].x += hv * u.x;
                acc[m].y += hv * u.y;
                acc[m].z += hv * u.z;
                acc[m].w += hv * u.w;
            }
        }
        // reduce over the 8 k-slices within each wave (lane bits 3..5)
        #pragma unroll
        for (int off = 8; off <= 32; off <<= 1) {
            #pragma unroll
            for (int m = 0; m < TBATCH; ++m) {
                acc[m].x += __shfl_xor(acc[m].x, off, 64);
                acc[m].y += __shfl_xor(acc[m].y, off, 64);
                acc[m].z += __shfl_xor(acc[m].z, off, 64);
                acc[m].w += __shfl_xor(acc[m].w, off, 64);
            }
        }
        if (lane < 8) {
            #pragma unroll
            for (int m = 0; m < TBATCH; ++m)
                *(float4*)(&red[wave][m][r4]) = acc[m];
        }
        __syncthreads();
        if (t < TBATCH * RANK) {
            int m = t >> 5, rr = t & 31;
            inter[m * RANK + rr] = red[0][m][rr] + red[1][m][rr] + red[2][m][rr] + red[3][m][rr];
        }
        __syncthreads();

        // ---- phase 3: pert[m][c..c+3] = sum_r inter[m][r] * V[r][c..c+3] ----
        float4 p[TBATCH];
        #pragma unroll
        for (int m = 0; m < TBATCH; ++m) p[m] = make_float4(0.f, 0.f, 0.f, 0.f);
        #pragma unroll 8
        for (int r = 0; r < RANK; ++r) {
            float4 v = *(const float4*)(Va + r * HIDDEN + c);
            #pragma unroll
            for (int m = 0; m < TBATCH; ++m) {
                float ir = inter[m * RANK + r];   // LDS broadcast
                p[m].x += ir * v.x;
                p[m].y += ir * v.y;
                p[m].z += ir * v.z;
                p[m].w += ir * v.w;
            }
        }

        // ---- d = h + alpha*pert; batched LayerNorm stats ----
        float4 dmv[TBATCH];
        float s[TBATCH], q[TBATCH];
        #pragma unroll
        for (int m = 0; m < TBATCH; ++m) {
            float4 hv = *(const float4*)(&Hs[m][c]);
            float4 d;
            d.x = hv.x + alpha * p[m].x;
            d.y = hv.y + alpha * p[m].y;
            d.z = hv.z + alpha * p[m].z;
            d.w = hv.w + alpha * p[m].w;
            dmv[m] = d;
            s[m] = d.x + d.y + d.z + d.w;
            q[m] = d.x * d.x + d.y * d.y + d.z * d.z + d.w * d.w;
        }
        #pragma unroll
        for (int off = 32; off > 0; off >>= 1) {
            #pragma unroll
            for (int m = 0; m < TBATCH; ++m) {
                s[m] += __shfl_xor(s[m], off, 64);
                q[m] += __shfl_xor(q[m], off, 64);
            }
        }
        if (lane == 0) {
            #pragma unroll
            for (int m = 0; m < TBATCH; ++m) {   // static indices only
                wred[wave][0][m] = s[m];
                wred[wave][1][m] = q[m];
            }
        }
        __syncthreads();

        // stats computed redundantly by every thread (16 LDS broadcasts + 4 rsqrt
        // beats a barrier + second LDS round-trip)
        float mean[TBATCH], rstd[TBATCH];
        #pragma unroll
        for (int m = 0; m < TBATCH; ++m) {
            float S = wred[0][0][m] + wred[1][0][m] + wred[2][0][m] + wred[3][0][m];
            float Q = wred[0][1][m] + wred[1][1][m] + wred[2][1][m] + wred[3][1][m];
            float mn = S * (1.0f / HIDDEN);
            mean[m] = mn;
            rstd[m] = rsqrtf(Q * (1.0f / HIDDEN) - mn * mn + LN_EPS);
        }

        // ---- normalize + write (compile-time m, uniform guard, streaming store) ----
        #pragma unroll
        for (int m = 0; m < TBATCH; ++m) {
            if (m < nm) {                         // nm is block-uniform
                float4 d = dmv[m];
                f32x4 o;
                o.x = (d.x - mean[m]) * rstd[m] * gv.x + bv.x;
                o.y = (d.y - mean[m]) * rstd[m] * gv.y + bv.y;
                o.z = (d.z - mean[m]) * rstd[m] * gv.z + bv.z;
                o.w = (d.w - mean[m]) * rstd[m] * gv.w + bv.w;
                __builtin_nontemporal_store(o, (f32x4*)(out + (size_t)tk[m] * HIDDEN + c));
            }
        }
        if (g + TBATCH < cnt) __syncthreads();    // protect Hs/red only if another group follows
    }
}

extern "C" void kernel_launch(void* const* d_in, const int* in_sizes, int n_in,
                              void* d_out, int out_size, void* d_ws, size_t ws_size,
                              hipStream_t stream) {
    const float* h     = (const float*)d_in[0];
    const float* la    = (const float*)d_in[1];
    const float* gamma = (const float*)d_in[2];
    const float* beta  = (const float*)d_in[3];
    const float* U     = (const float*)d_in[4];
    const float* V     = (const float*)d_in[5];
    const int* ids     = (const int*)d_in[6];
    float* out         = (float*)d_out;

    div_inject_kernel<<<NUM_AGENTS * SPLITS, 256, 0, stream>>>(
        h, la, gamma, beta, U, V, ids, out);
}